// Round 7
// baseline (574.140 us; speedup 1.0000x reference)
//
#include <hip/hip_runtime.h>
#include <hip/hip_bf16.h>

typedef __bf16 bf16_t;
typedef __bf16 bf16x8 __attribute__((ext_vector_type(8)));
typedef float  f32x4  __attribute__((ext_vector_type(4)));

#define CIN  64
#define COUT 128
#define HH   224
#define WW   224
#define OH   222
#define OW   222
#define HW   (HH * WW)
#define XT_RS 72   // padded ci-stride: 144 B rows, 16B-aligned, 2-way banks max

// -------- prepack: wpk[off][co][ci] = bf16(w[co][ci][kh][kw]), off = kh*3+kw
__global__ void prepack_w(const float* __restrict__ w, bf16_t* __restrict__ wpk) {
    int idx = blockIdx.x * 256 + threadIdx.x;
    if (idx >= 9 * COUT * CIN) return;
    int ci  = idx & 63;
    int co  = (idx >> 6) & 127;
    int off = idx >> 13;
    wpk[idx] = (bf16_t)w[(co * CIN + ci) * 9 + off];
}

// -------- transform: x NCHW fp32 -> x2 NHWC bf16 (streaming both sides)
// Per block: one (b, h, 32-w) tile. Reads 64 ci-rows x 128 B contiguous;
// writes 32 pixels x 128 B contiguous. LDS transpose, XOR-swizzled banks.
__global__ __launch_bounds__(256) void transform_x(
    const float* __restrict__ x, bf16_t* __restrict__ x2)
{
    __shared__ __align__(16) bf16_t lt[32][XT_RS];
    const int tid = threadIdx.x;
    const int w0 = blockIdx.x * 32;
    const int h  = blockIdx.y;
    const int b  = blockIdx.z;
    const float* xb = x + (size_t)b * CIN * HW + h * WW + w0;
#pragma unroll
    for (int it = 0; it < 2; ++it) {
        int idx = it * 256 + tid;
        int ci = idx >> 3;          // 0..63
        int w4 = idx & 7;           // which float4 along w
        float4 v = *reinterpret_cast<const float4*>(xb + (size_t)ci * HW + w4 * 4);
        // swizzle: ci' = ci ^ (w4<<3) keeps 8-aligned blocks, spreads banks
        lt[w4 * 4 + 0][ci ^ (w4 << 3)] = (bf16_t)v.x;
        lt[w4 * 4 + 1][ci ^ (w4 << 3)] = (bf16_t)v.y;
        lt[w4 * 4 + 2][ci ^ (w4 << 3)] = (bf16_t)v.z;
        lt[w4 * 4 + 3][ci ^ (w4 << 3)] = (bf16_t)v.w;
    }
    __syncthreads();
    int w  = tid >> 3;              // 0..31
    int c8 = tid & 7;               // 8-ci group
    uint4 val = *reinterpret_cast<const uint4*>(
        &lt[w][(c8 * 8) ^ (((w >> 2) & 7) << 3)]);
    bf16_t* dst = x2 + ((size_t)b * HW + h * WW + w0 + w) * CIN + c8 * 8;
    *reinterpret_cast<uint4*>(dst) = val;
}

// -------- main: implicit-GEMM conv + bias + channel-min + tanh(tanh), NHWC in
__global__ __launch_bounds__(256) void conv_min_tanh_nhwc(
    const bf16_t* __restrict__ x2, const float* __restrict__ bias,
    const bf16_t* __restrict__ wpk, float* __restrict__ out)
{
    __shared__ __align__(16) bf16_t xt[180 * XT_RS];   // 25,920 B
    __shared__ float red[2][8][16];                     // 1 KB

    const int tid = threadIdx.x;
    const int lane = tid & 63;
    const int wv  = tid >> 6;
    const int wgM = wv >> 1;
    const int wgN = wv & 1;
    const int l15 = lane & 15;
    const int lg  = lane >> 4;

    const int owb = blockIdx.x * 16;
    const int ohb = blockIdx.y * 8;
    const int b   = blockIdx.z;

    // ---- stage x tile from NHWC bf16: 180 pixels x 128 B, burst-friendly
    const bf16_t* x2b = x2 + (size_t)b * HW * CIN;
    for (int i = tid; i < 1440; i += 256) {
        int c8  = i & 7;
        int pix = i >> 3;               // 0..179 = r*18 + c
        int r = pix / 18, c = pix - r * 18;
        int rg = ohb + r; if (rg > HH - 1) rg = HH - 1;   // clamp feeds only
        int cg = owb + c; if (cg > WW - 1) cg = WW - 1;   // discarded outputs
        uint4 v = *reinterpret_cast<const uint4*>(
            x2b + ((size_t)rg * WW + cg) * CIN + c8 * 8);
        *reinterpret_cast<uint4*>(&xt[pix * XT_RS + c8 * 8]) = v;
    }

    float bias4[4];
#pragma unroll
    for (int ni = 0; ni < 4; ni++) bias4[ni] = bias[wgN * 64 + ni * 16 + l15];

    f32x4 acc[4][4];
#pragma unroll
    for (int mi = 0; mi < 4; mi++)
#pragma unroll
        for (int ni = 0; ni < 4; ni++)
            acc[mi][ni] = (f32x4){0.f, 0.f, 0.f, 0.f};

    __syncthreads();   // xt ready — only pre-epilogue barrier

    const bf16_t* wb = wpk + (size_t)(wgN * 64 + l15) * CIN + lg * 8;

    // ---- 9 taps x 2 K-steps of 32 ci; weights register-direct from L2 wpk
#pragma unroll 1
    for (int off = 0; off < 9; off++) {
        const int kh = off / 3, kw = off - 3 * kh;

        bf16x8 bfr[2][4];
        {
            const bf16_t* wt = wb + (size_t)off * (COUT * CIN);
#pragma unroll
            for (int kk = 0; kk < 2; kk++)
#pragma unroll
                for (int ni = 0; ni < 4; ni++)
                    bfr[kk][ni] = *reinterpret_cast<const bf16x8*>(
                        wt + ni * 16 * CIN + kk * 32);
        }

#pragma unroll
        for (int kk = 0; kk < 2; kk++) {
            bf16x8 af[4];
#pragma unroll
            for (int mi = 0; mi < 4; mi++) {
                int row = wgM * 4 + mi + kh;
                int col = l15 + kw;
                af[mi] = *reinterpret_cast<const bf16x8*>(
                    &xt[(row * 18 + col) * XT_RS + kk * 32 + lg * 8]);
            }
#pragma unroll
            for (int mi = 0; mi < 4; mi++)
#pragma unroll
                for (int ni = 0; ni < 4; ni++)
                    acc[mi][ni] = __builtin_amdgcn_mfma_f32_16x16x32_bf16(
                        af[mi], bfr[kk][ni], acc[mi][ni], 0, 0, 0);
        }
    }

    // ---- epilogue: +bias, min over ni, min over co-lanes, min across wgN, tanh^2
#pragma unroll
    for (int mi = 0; mi < 4; mi++) {
#pragma unroll
        for (int r = 0; r < 4; r++) {
            float v =        acc[mi][0][r] + bias4[0];
            v = fminf(v,     acc[mi][1][r] + bias4[1]);
            v = fminf(v,     acc[mi][2][r] + bias4[2]);
            v = fminf(v,     acc[mi][3][r] + bias4[3]);
            v = fminf(v, __shfl_xor(v, 1));
            v = fminf(v, __shfl_xor(v, 2));
            v = fminf(v, __shfl_xor(v, 4));
            v = fminf(v, __shfl_xor(v, 8));
            if (l15 == 0) red[wgN][wgM * 4 + mi][lg * 4 + r] = v;
        }
    }
    __syncthreads();
    if (tid < 128) {
        int prow = tid >> 4, pcol = tid & 15;
        float v = fminf(red[0][prow][pcol], red[1][prow][pcol]);
        v = tanhf(tanhf(v));
        int oh = ohb + prow, ow = owb + pcol;
        if (oh < OH && ow < OW)
            out[((size_t)b * OH + oh) * OW + ow] = v;
    }
}

// -------- fallback (R6): NCHW direct staging, used only if d_ws too small
__global__ __launch_bounds__(256) void conv_min_tanh_nchw(
    const float* __restrict__ x, const float* __restrict__ w,
    const float* __restrict__ bias, const bf16_t* __restrict__ wpk,
    float* __restrict__ out)
{
    __shared__ __align__(16) bf16_t xt[180 * XT_RS];
    __shared__ float red[2][8][16];

    const int tid = threadIdx.x;
    const int lane = tid & 63;
    const int wv  = tid >> 6;
    const int wgM = wv >> 1;
    const int wgN = wv & 1;
    const int l15 = lane & 15;
    const int lg  = lane >> 4;

    const int owb = blockIdx.x * 16;
    const int ohb = blockIdx.y * 8;
    const int b   = blockIdx.z;

    const float* xb = x + (size_t)b * (CIN * HH * WW);
    for (int i = tid; i < 2560; i += 256) {
        int c4 = i & 3;
        int r  = (i >> 2) % 10;
        int ci = i / 40;
        int rg = ohb + r; if (rg > HH - 1) rg = HH - 1;
        float4 v = *reinterpret_cast<const float4*>(
            &xb[(ci * HH + rg) * WW + owb + 4 * c4]);
        bf16_t* dst = &xt[(r * 18 + 4 * c4) * XT_RS + ci];
        dst[0 * XT_RS] = (bf16_t)v.x;
        dst[1 * XT_RS] = (bf16_t)v.y;
        dst[2 * XT_RS] = (bf16_t)v.z;
        dst[3 * XT_RS] = (bf16_t)v.w;
    }
    for (int i = tid; i < 640; i += 256) {
        int r  = i % 10;
        int ci = i / 10;
        int rg = ohb + r; if (rg > HH - 1) rg = HH - 1;
        int cg = owb + 16;
        float2 v;
        if (cg + 1 <= WW - 1) {
            v = *reinterpret_cast<const float2*>(&xb[(ci * HH + rg) * WW + cg]);
        } else {
            float a = xb[(ci * HH + rg) * WW + (WW - 1)];
            v = make_float2(a, a);
        }
        bf16_t* dst = &xt[(r * 18 + 16) * XT_RS + ci];
        dst[0 * XT_RS] = (bf16_t)v.x;
        dst[1 * XT_RS] = (bf16_t)v.y;
    }

    float bias4[4];
#pragma unroll
    for (int ni = 0; ni < 4; ni++) bias4[ni] = bias[wgN * 64 + ni * 16 + l15];

    f32x4 acc[4][4];
#pragma unroll
    for (int mi = 0; mi < 4; mi++)
#pragma unroll
        for (int ni = 0; ni < 4; ni++)
            acc[mi][ni] = (f32x4){0.f, 0.f, 0.f, 0.f};

    __syncthreads();

    const bf16_t* wb = wpk ? wpk + (size_t)(wgN * 64 + l15) * CIN + lg * 8 : nullptr;

#pragma unroll 1
    for (int off = 0; off < 9; off++) {
        const int kh = off / 3, kw = off - 3 * kh;
        bf16x8 bfr[2][4];
        if (wb) {
            const bf16_t* wt = wb + (size_t)off * (COUT * CIN);
#pragma unroll
            for (int kk = 0; kk < 2; kk++)
#pragma unroll
                for (int ni = 0; ni < 4; ni++)
                    bfr[kk][ni] = *reinterpret_cast<const bf16x8*>(
                        wt + ni * 16 * CIN + kk * 32);
        } else {
#pragma unroll
            for (int kk = 0; kk < 2; kk++)
#pragma unroll
                for (int ni = 0; ni < 4; ni++) {
                    int co = wgN * 64 + ni * 16 + l15;
                    bf16x8 t;
#pragma unroll
                    for (int j = 0; j < 8; j++)
                        t[j] = (bf16_t)w[(co * CIN + kk * 32 + lg * 8 + j) * 9 + off];
                    bfr[kk][ni] = t;
                }
        }
#pragma unroll
        for (int kk = 0; kk < 2; kk++) {
            bf16x8 af[4];
#pragma unroll
            for (int mi = 0; mi < 4; mi++) {
                int row = wgM * 4 + mi + kh;
                int col = l15 + kw;
                af[mi] = *reinterpret_cast<const bf16x8*>(
                    &xt[(row * 18 + col) * XT_RS + kk * 32 + lg * 8]);
            }
#pragma unroll
            for (int mi = 0; mi < 4; mi++)
#pragma unroll
                for (int ni = 0; ni < 4; ni++)
                    acc[mi][ni] = __builtin_amdgcn_mfma_f32_16x16x32_bf16(
                        af[mi], bfr[kk][ni], acc[mi][ni], 0, 0, 0);
        }
    }

#pragma unroll
    for (int mi = 0; mi < 4; mi++) {
#pragma unroll
        for (int r = 0; r < 4; r++) {
            float v =        acc[mi][0][r] + bias4[0];
            v = fminf(v,     acc[mi][1][r] + bias4[1]);
            v = fminf(v,     acc[mi][2][r] + bias4[2]);
            v = fminf(v,     acc[mi][3][r] + bias4[3]);
            v = fminf(v, __shfl_xor(v, 1));
            v = fminf(v, __shfl_xor(v, 2));
            v = fminf(v, __shfl_xor(v, 4));
            v = fminf(v, __shfl_xor(v, 8));
            if (l15 == 0) red[wgN][wgM * 4 + mi][lg * 4 + r] = v;
        }
    }
    __syncthreads();
    if (tid < 128) {
        int prow = tid >> 4, pcol = tid & 15;
        float v = fminf(red[0][prow][pcol], red[1][prow][pcol]);
        v = tanhf(tanhf(v));
        int oh = ohb + prow, ow = owb + pcol;
        if (oh < OH && ow < OW)
            out[((size_t)b * OH + oh) * OW + ow] = v;
    }
}

extern "C" void kernel_launch(void* const* d_in, const int* in_sizes, int n_in,
                              void* d_out, int out_size, void* d_ws, size_t ws_size,
                              hipStream_t stream) {
    const float* x    = (const float*)d_in[0];
    const float* w    = (const float*)d_in[1];
    const float* bias = (const float*)d_in[2];
    float* out = (float*)d_out;

    const size_t X2_BYTES  = (size_t)16 * HW * CIN * sizeof(bf16_t);  // 102,760,448
    const size_t WPK_BYTES = (size_t)9 * COUT * CIN * sizeof(bf16_t); // 147,456
    dim3 grid(14, 28, 16);

    if (ws_size >= X2_BYTES + WPK_BYTES) {
        bf16_t* x2  = (bf16_t*)d_ws;
        bf16_t* wpk = (bf16_t*)((char*)d_ws + X2_BYTES);
        prepack_w<<<288, 256, 0, stream>>>(w, wpk);
        transform_x<<<dim3(7, 224, 16), 256, 0, stream>>>(x, x2);
        conv_min_tanh_nhwc<<<grid, 256, 0, stream>>>(x2, bias, wpk, out);
    } else if (ws_size >= WPK_BYTES) {
        bf16_t* wpk = (bf16_t*)d_ws;
        prepack_w<<<288, 256, 0, stream>>>(w, wpk);
        conv_min_tanh_nchw<<<grid, 256, 0, stream>>>(x, w, bias, wpk, out);
    } else {
        conv_min_tanh_nchw<<<grid, 256, 0, stream>>>(x, w, bias, nullptr, out);
    }
}

// Round 8
// 418.870 us; speedup vs baseline: 1.3707x; 1.3707x over previous
//
#include <hip/hip_runtime.h>
#include <hip/hip_bf16.h>

typedef __bf16 bf16_t;
typedef __bf16 bf16x8 __attribute__((ext_vector_type(8)));
typedef float  f32x4  __attribute__((ext_vector_type(4)));

#define CIN  64
#define COUT 128
#define HH   224
#define WW   224
#define OH   222
#define OW   222
#define HW   (HH * WW)
#define XT_RS 72   // padded ci-stride: 144 B rows, 16B-aligned, balanced banks

// -------- prepack: wpk[off][co][ci] = bf16(w[co][ci][kh][kw]), off = kh*3+kw
__global__ void prepack_w(const float* __restrict__ w, bf16_t* __restrict__ wpk) {
    int idx = blockIdx.x * 256 + threadIdx.x;
    if (idx >= 9 * COUT * CIN) return;
    int ci  = idx & 63;
    int co  = (idx >> 6) & 127;
    int off = idx >> 13;
    wpk[idx] = (bf16_t)w[(co * CIN + ci) * 9 + off];
}

// -------- transform: x NCHW fp32 -> x2 NHWC bf16 (unchanged from R7, verified)
__global__ __launch_bounds__(256) void transform_x(
    const float* __restrict__ x, bf16_t* __restrict__ x2)
{
    __shared__ __align__(16) bf16_t lt[32][XT_RS];
    const int tid = threadIdx.x;
    const int w0 = blockIdx.x * 32;
    const int h  = blockIdx.y;
    const int b  = blockIdx.z;
    const float* xb = x + (size_t)b * CIN * HW + h * WW + w0;
#pragma unroll
    for (int it = 0; it < 2; ++it) {
        int idx = it * 256 + tid;
        int ci = idx >> 3;
        int w4 = idx & 7;
        float4 v = *reinterpret_cast<const float4*>(xb + (size_t)ci * HW + w4 * 4);
        lt[w4 * 4 + 0][ci ^ (w4 << 3)] = (bf16_t)v.x;
        lt[w4 * 4 + 1][ci ^ (w4 << 3)] = (bf16_t)v.y;
        lt[w4 * 4 + 2][ci ^ (w4 << 3)] = (bf16_t)v.z;
        lt[w4 * 4 + 3][ci ^ (w4 << 3)] = (bf16_t)v.w;
    }
    __syncthreads();
    int w  = tid >> 3;
    int c8 = tid & 7;
    uint4 val = *reinterpret_cast<const uint4*>(
        &lt[w][(c8 * 8) ^ (((w >> 2) & 7) << 3)]);
    bf16_t* dst = x2 + ((size_t)b * HW + h * WW + w0 + w) * CIN + c8 * 8;
    *reinterpret_cast<uint4*>(dst) = val;
}

// -------- main: 512-thread / 256-pixel blocks; NHWC x2; LDS-staged weights
// with register double-buffer (R5 scheme). 8 waves = 4 M-groups x 2 N-groups.
__global__ __launch_bounds__(512, 4) void conv_min_tanh_nhwc(
    const bf16_t* __restrict__ x2, const float* __restrict__ bias,
    const bf16_t* __restrict__ wpk, float* __restrict__ out)
{
    __shared__ __align__(16) bf16_t xt[18 * 18 * XT_RS];  // 46,656 B
    __shared__ __align__(16) bf16_t wl[COUT * XT_RS];     // 18,432 B
    __shared__ float red[2][16][16];                       // 2 KB (67.1 KB total)

    const int tid = threadIdx.x;
    const int lane = tid & 63;
    const int wv  = tid >> 6;       // 0..7
    const int wgM = wv >> 1;        // 0..3: pixel rows wgM*4 .. wgM*4+3
    const int wgN = wv & 1;         // 0..1: co 0-63 / 64-127
    const int l15 = lane & 15;
    const int lg  = lane >> 4;

    const int owb = blockIdx.x * 16;
    const int ohb = blockIdx.y * 16;
    const int b   = blockIdx.z;

    // weight-stage identity: thread stages 32 B of wl (co = tid>>2, 16-ci quarter)
    const int wco = tid >> 2, wq = tid & 3;

    // ---- prefetch tap-0 weights into registers
    uint4 wreg0, wreg1;
    {
        const uint4* src = reinterpret_cast<const uint4*>(
            wpk + (size_t)wco * CIN + wq * 16);
        wreg0 = src[0]; wreg1 = src[1];
    }

    // ---- stage x tile from NHWC: 324 pixels x 128 B (rows 2.3 KB contiguous)
    const bf16_t* x2b = x2 + (size_t)b * HW * CIN;
    for (int i = tid; i < 2592; i += 512) {
        int c8  = i & 7;
        int pix = i >> 3;               // 0..323 = r*18 + c
        int r = pix / 18, c = pix - r * 18;
        int rg = ohb + r; if (rg > HH - 1) rg = HH - 1;   // clamp feeds only
        int cg = owb + c; if (cg > WW - 1) cg = WW - 1;   // discarded outputs
        uint4 v = *reinterpret_cast<const uint4*>(
            x2b + ((size_t)rg * WW + cg) * CIN + c8 * 8);
        *reinterpret_cast<uint4*>(&xt[pix * XT_RS + c8 * 8]) = v;
    }

    float bias4[4];
#pragma unroll
    for (int ni = 0; ni < 4; ni++) bias4[ni] = bias[wgN * 64 + ni * 16 + l15];

    f32x4 acc[4][4];
#pragma unroll
    for (int mi = 0; mi < 4; mi++)
#pragma unroll
        for (int ni = 0; ni < 4; ni++)
            acc[mi][ni] = (f32x4){0.f, 0.f, 0.f, 0.f};

    __syncthreads();   // xt ready; wl writable

    // ---- 9 taps; per tap: drain wreg->wl, prefetch next, barrier, compute
#pragma unroll 1
    for (int off = 0; off < 9; off++) {
        {
            uint4* dst = reinterpret_cast<uint4*>(&wl[wco * XT_RS + wq * 16]);
            dst[0] = wreg0; dst[1] = wreg1;
        }
        if (off < 8) {
            const uint4* src = reinterpret_cast<const uint4*>(
                wpk + (size_t)(off + 1) * (COUT * CIN) + wco * CIN + wq * 16);
            wreg0 = src[0]; wreg1 = src[1];
        }
        __syncthreads();   // wl[off] visible

        const int kh = off / 3, kw = off - 3 * kh;
#pragma unroll
        for (int kk = 0; kk < 2; kk++) {
            bf16x8 af[4], bfr[4];
#pragma unroll
            for (int mi = 0; mi < 4; mi++) {
                int row = wgM * 4 + mi + kh;       // input row in 18-row tile
                int col = l15 + kw;                // input col (M-dim = l15)
                af[mi] = *reinterpret_cast<const bf16x8*>(
                    &xt[(row * 18 + col) * XT_RS + kk * 32 + lg * 8]);
            }
#pragma unroll
            for (int ni = 0; ni < 4; ni++) {
                int co = wgN * 64 + ni * 16 + l15;
                bfr[ni] = *reinterpret_cast<const bf16x8*>(
                    &wl[co * XT_RS + kk * 32 + lg * 8]);
            }
#pragma unroll
            for (int mi = 0; mi < 4; mi++)
#pragma unroll
                for (int ni = 0; ni < 4; ni++)
                    acc[mi][ni] = __builtin_amdgcn_mfma_f32_16x16x32_bf16(
                        af[mi], bfr[ni], acc[mi][ni], 0, 0, 0);
        }

        if (off < 8) __syncthreads();   // readers done before next wl write
    }

    // ---- epilogue: +bias, min over ni, min over 16 co-lanes, min across wgN
#pragma unroll
    for (int mi = 0; mi < 4; mi++) {
#pragma unroll
        for (int r = 0; r < 4; r++) {
            float v =        acc[mi][0][r] + bias4[0];
            v = fminf(v,     acc[mi][1][r] + bias4[1]);
            v = fminf(v,     acc[mi][2][r] + bias4[2]);
            v = fminf(v,     acc[mi][3][r] + bias4[3]);
            v = fminf(v, __shfl_xor(v, 1));
            v = fminf(v, __shfl_xor(v, 2));
            v = fminf(v, __shfl_xor(v, 4));
            v = fminf(v, __shfl_xor(v, 8));
            if (l15 == 0) red[wgN][wgM * 4 + mi][lg * 4 + r] = v;
        }
    }
    __syncthreads();
    if (tid < 256) {
        int prow = tid >> 4, pcol = tid & 15;
        float v = fminf(red[0][prow][pcol], red[1][prow][pcol]);
        v = tanhf(tanhf(v));
        int oh = ohb + prow, ow = owb + pcol;
        if (oh < OH && ow < OW)
            out[((size_t)b * OH + oh) * OW + ow] = v;
    }
}

// -------- fallback (R6 structure): NCHW direct, if d_ws too small for x2
__global__ __launch_bounds__(256) void conv_min_tanh_nchw(
    const float* __restrict__ x, const float* __restrict__ w,
    const float* __restrict__ bias, const bf16_t* __restrict__ wpk,
    float* __restrict__ out)
{
    __shared__ __align__(16) bf16_t xt[180 * XT_RS];
    __shared__ float red[2][8][16];

    const int tid = threadIdx.x;
    const int lane = tid & 63;
    const int wv  = tid >> 6;
    const int wgM = wv >> 1;
    const int wgN = wv & 1;
    const int l15 = lane & 15;
    const int lg  = lane >> 4;

    const int owb = blockIdx.x * 16;
    const int ohb = blockIdx.y * 8;
    const int b   = blockIdx.z;

    const float* xb = x + (size_t)b * (CIN * HH * WW);
    for (int i = tid; i < 2560; i += 256) {
        int c4 = i & 3;
        int r  = (i >> 2) % 10;
        int ci = i / 40;
        int rg = ohb + r; if (rg > HH - 1) rg = HH - 1;
        float4 v = *reinterpret_cast<const float4*>(
            &xb[(ci * HH + rg) * WW + owb + 4 * c4]);
        bf16_t* dst = &xt[(r * 18 + 4 * c4) * XT_RS + ci];
        dst[0 * XT_RS] = (bf16_t)v.x;
        dst[1 * XT_RS] = (bf16_t)v.y;
        dst[2 * XT_RS] = (bf16_t)v.z;
        dst[3 * XT_RS] = (bf16_t)v.w;
    }
    for (int i = tid; i < 640; i += 256) {
        int r  = i % 10;
        int ci = i / 10;
        int rg = ohb + r; if (rg > HH - 1) rg = HH - 1;
        int cg = owb + 16;
        float2 v;
        if (cg + 1 <= WW - 1) {
            v = *reinterpret_cast<const float2*>(&xb[(ci * HH + rg) * WW + cg]);
        } else {
            float a = xb[(ci * HH + rg) * WW + (WW - 1)];
            v = make_float2(a, a);
        }
        bf16_t* dst = &xt[(r * 18 + 16) * XT_RS + ci];
        dst[0 * XT_RS] = (bf16_t)v.x;
        dst[1 * XT_RS] = (bf16_t)v.y;
    }

    float bias4[4];
#pragma unroll
    for (int ni = 0; ni < 4; ni++) bias4[ni] = bias[wgN * 64 + ni * 16 + l15];

    f32x4 acc[4][4];
#pragma unroll
    for (int mi = 0; mi < 4; mi++)
#pragma unroll
        for (int ni = 0; ni < 4; ni++)
            acc[mi][ni] = (f32x4){0.f, 0.f, 0.f, 0.f};

    __syncthreads();

    const bf16_t* wb = wpk ? wpk + (size_t)(wgN * 64 + l15) * CIN + lg * 8 : nullptr;

#pragma unroll 1
    for (int off = 0; off < 9; off++) {
        const int kh = off / 3, kw = off - 3 * kh;
        bf16x8 bfr[2][4];
        if (wb) {
            const bf16_t* wt = wb + (size_t)off * (COUT * CIN);
#pragma unroll
            for (int kk = 0; kk < 2; kk++)
#pragma unroll
                for (int ni = 0; ni < 4; ni++)
                    bfr[kk][ni] = *reinterpret_cast<const bf16x8*>(
                        wt + ni * 16 * CIN + kk * 32);
        } else {
#pragma unroll
            for (int kk = 0; kk < 2; kk++)
#pragma unroll
                for (int ni = 0; ni < 4; ni++) {
                    int co = wgN * 64 + ni * 16 + l15;
                    bf16x8 t;
#pragma unroll
                    for (int j = 0; j < 8; j++)
                        t[j] = (bf16_t)w[(co * CIN + kk * 32 + lg * 8 + j) * 9 + off];
                    bfr[kk][ni] = t;
                }
        }
#pragma unroll
        for (int kk = 0; kk < 2; kk++) {
            bf16x8 af[4];
#pragma unroll
            for (int mi = 0; mi < 4; mi++) {
                int row = wgM * 4 + mi + kh;
                int col = l15 + kw;
                af[mi] = *reinterpret_cast<const bf16x8*>(
                    &xt[(row * 18 + col) * XT_RS + kk * 32 + lg * 8]);
            }
#pragma unroll
            for (int mi = 0; mi < 4; mi++)
#pragma unroll
                for (int ni = 0; ni < 4; ni++)
                    acc[mi][ni] = __builtin_amdgcn_mfma_f32_16x16x32_bf16(
                        af[mi], bfr[kk][ni], acc[mi][ni], 0, 0, 0);
        }
    }

#pragma unroll
    for (int mi = 0; mi < 4; mi++) {
#pragma unroll
        for (int r = 0; r < 4; r++) {
            float v =        acc[mi][0][r] + bias4[0];
            v = fminf(v,     acc[mi][1][r] + bias4[1]);
            v = fminf(v,     acc[mi][2][r] + bias4[2]);
            v = fminf(v,     acc[mi][3][r] + bias4[3]);
            v = fminf(v, __shfl_xor(v, 1));
            v = fminf(v, __shfl_xor(v, 2));
            v = fminf(v, __shfl_xor(v, 4));
            v = fminf(v, __shfl_xor(v, 8));
            if (l15 == 0) red[wgN][wgM * 4 + mi][lg * 4 + r] = v;
        }
    }
    __syncthreads();
    if (tid < 128) {
        int prow = tid >> 4, pcol = tid & 15;
        float v = fminf(red[0][prow][pcol], red[1][prow][pcol]);
        v = tanhf(tanhf(v));
        int oh = ohb + prow, ow = owb + pcol;
        if (oh < OH && ow < OW)
            out[((size_t)b * OH + oh) * OW + ow] = v;
    }
}

extern "C" void kernel_launch(void* const* d_in, const int* in_sizes, int n_in,
                              void* d_out, int out_size, void* d_ws, size_t ws_size,
                              hipStream_t stream) {
    const float* x    = (const float*)d_in[0];
    const float* w    = (const float*)d_in[1];
    const float* bias = (const float*)d_in[2];
    float* out = (float*)d_out;

    const size_t X2_BYTES  = (size_t)16 * HW * CIN * sizeof(bf16_t);  // 102,760,448
    const size_t WPK_BYTES = (size_t)9 * COUT * CIN * sizeof(bf16_t); // 147,456

    if (ws_size >= X2_BYTES + WPK_BYTES) {
        bf16_t* x2  = (bf16_t*)d_ws;
        bf16_t* wpk = (bf16_t*)((char*)d_ws + X2_BYTES);
        prepack_w<<<288, 256, 0, stream>>>(w, wpk);
        transform_x<<<dim3(7, 224, 16), 256, 0, stream>>>(x, x2);
        conv_min_tanh_nhwc<<<dim3(14, 14, 16), 512, 0, stream>>>(x2, bias, wpk, out);
    } else if (ws_size >= WPK_BYTES) {
        bf16_t* wpk = (bf16_t*)d_ws;
        prepack_w<<<288, 256, 0, stream>>>(w, wpk);
        conv_min_tanh_nchw<<<dim3(14, 28, 16), 256, 0, stream>>>(x, w, bias, wpk, out);
    } else {
        conv_min_tanh_nchw<<<dim3(14, 28, 16), 256, 0, stream>>>(x, w, bias, nullptr, out);
    }
}